// Round 4
// baseline (1728.265 us; speedup 1.0000x reference)
//
#include <hip/hip_runtime.h>
#include <math.h>

#define NPTS 4096
#define NBATCH 4
#define BLOCK 256
#define RPW 8            // rows per wave
#define NCH 4            // skip-granularity chunks (1024 cols each = 16 float4/lane)

static constexpr float KSCALE     = 1.4426950408889634f / 1e-4f;   // log2(e)/eps
static constexpr float INVK2      = 1.0f / (KSCALE * KSCALE);
static constexpr float EPSLN2     = 1e-4f * 0.6931471805599453f;   // eps*ln(2)
static constexpr float NEGEPSLOGW = 8.31776616671934e-4f;          // -eps * (-log(4096))
static constexpr float THR        = 25.0f;   // phase-B skip threshold (log2 units)

__device__ __forceinline__ float fexp2(float x){
#if __has_builtin(__builtin_amdgcn_exp2f)
  return __builtin_amdgcn_exp2f(x);
#else
  return exp2f(x);
#endif
}
__device__ __forceinline__ float flog2(float x){
#if __has_builtin(__builtin_amdgcn_logf)
  return __builtin_amdgcn_logf(x);
#else
  return log2f(x);
#endif
}

// Two-phase softmin, one launch = two independent problems (512 blocks each).
// Block = 256 thr = 4 independent waves (no LDS, no barriers).
// Wave owns 8 rows; columns lane-distinct (lane l owns cols l+64j).
// Phase A: dots + max3 trees only -> cmax[chunk][row]; shfl-max -> global m[row].
// Phase B: re-dot + exp2 ONLY for chunks with __any(cmax > m - THR).
// Loads are batched (8x dwordx4) and pinned with sched_barrier(0) so the
// compiler cannot sink them into the row loops (R2's 48-VGPR failure mode).
__global__ __launch_bounds__(BLOCK, 4) void softmin_kernel(
    const float* __restrict__ rowA, int rsA, const float4* __restrict__ pkInA,
    float4* __restrict__ pkOutA, const float* __restrict__ hOldA,
    float* __restrict__ outA, int modeA,
    const float* __restrict__ rowB, int rsB, const float4* __restrict__ pkInB,
    float4* __restrict__ pkOutB, const float* __restrict__ hOldB,
    float* __restrict__ outB, int modeB)
{
  int bid = blockIdx.x;
  const float* rowp; const float4* pkin; float4* pkout; const float* hold;
  float* outp; int rs, mode;
  if (bid < 512) { rowp=rowA; pkin=pkInA; pkout=pkOutA; hold=hOldA; outp=outA; rs=rsA; mode=modeA; }
  else           { rowp=rowB; pkin=pkInB; pkout=pkOutB; hold=hOldB; outp=outB; rs=rsB; mode=modeB; }
  int lb = bid & 511;
  int b  = lb >> 7;          // batch
  int rb = lb & 127;         // row-block (32 rows per block)

  int tid = threadIdx.x;
  int w = tid >> 6, lane = tid & 63;
  int r0 = rb*32 + w*RPW;
  int ridx0 = b*NPTS + r0;

  float ptx[RPW], pty[RPW], ptz[RPW];
  #pragma unroll
  for (int i = 0; i < RPW; ++i) {
    const float* p = rowp + (size_t)(ridx0 + i) * rs;
    ptx[i] = p[0]*KSCALE; pty[i] = p[1]*KSCALE; ptz[i] = p[2]*KSCALE;
  }

  const float4* base = pkin + b*NPTS + lane;
  float4 q[8];
  float cmax[NCH][RPW];
  #pragma unroll
  for (int c = 0; c < NCH; ++c)
    #pragma unroll
    for (int r = 0; r < RPW; ++r) cmax[c][r] = -INFINITY;

#define LOADB(J0) do {                                                   \
    _Pragma("unroll")                                                    \
    for (int k = 0; k < 8; ++k) q[k] = base[((J0)+k)*64];                \
    __builtin_amdgcn_sched_barrier(0);                                   \
  } while(0)

#define DOTS_DECL(R)                                                     \
    float ax = ptx[R], ay = pty[R], az = ptz[R];                         \
    float t0 = fmaf(ax,q[0].x,fmaf(ay,q[0].y,fmaf(az,q[0].z,q[0].w)));   \
    float t1 = fmaf(ax,q[1].x,fmaf(ay,q[1].y,fmaf(az,q[1].z,q[1].w)));   \
    float t2 = fmaf(ax,q[2].x,fmaf(ay,q[2].y,fmaf(az,q[2].z,q[2].w)));   \
    float t3 = fmaf(ax,q[3].x,fmaf(ay,q[3].y,fmaf(az,q[3].z,q[3].w)));   \
    float t4 = fmaf(ax,q[4].x,fmaf(ay,q[4].y,fmaf(az,q[4].z,q[4].w)));   \
    float t5 = fmaf(ax,q[5].x,fmaf(ay,q[5].y,fmaf(az,q[5].z,q[5].w)));   \
    float t6 = fmaf(ax,q[6].x,fmaf(ay,q[6].y,fmaf(az,q[6].z,q[6].w)));   \
    float t7 = fmaf(ax,q[7].x,fmaf(ay,q[7].y,fmaf(az,q[7].z,q[7].w)));

#define PHA_HALF(C) do {                                                 \
    _Pragma("unroll")                                                    \
    for (int r = 0; r < RPW; ++r) {                                      \
      DOTS_DECL(r)                                                       \
      float u = fmaxf(fmaxf(t0,t1),t2);                                  \
      float v = fmaxf(fmaxf(t3,t4),t5);                                  \
      float z = fmaxf(fmaxf(t6,t7),cmax[C][r]);                          \
      cmax[C][r] = fmaxf(fmaxf(u,v),z);                                  \
    }                                                                    \
  } while(0)

  // ---- phase A: exact per-row global max ----
  LOADB(0);  PHA_HALF(0);
  LOADB(8);  PHA_HALF(0);
  LOADB(16); PHA_HALF(1);
  LOADB(24); PHA_HALF(1);
  LOADB(32); PHA_HALF(2);
  LOADB(40); PHA_HALF(2);
  LOADB(48); PHA_HALF(3);
  LOADB(56); PHA_HALF(3);

  float m[RPW];
  #pragma unroll
  for (int r = 0; r < RPW; ++r) {
    float mm = fmaxf(fmaxf(cmax[0][r],cmax[1][r]), fmaxf(cmax[2][r],cmax[3][r]));
    #pragma unroll
    for (int off = 32; off; off >>= 1) mm = fmaxf(mm, __shfl_xor(mm, off, 64));
    m[r] = mm;
  }

  // ---- phase B: sum of exp2 over active chunks only ----
  float S[RPW];
  #pragma unroll
  for (int r = 0; r < RPW; ++r) S[r] = 0.f;

#define PHB_HALF() do {                                                  \
    _Pragma("unroll")                                                    \
    for (int r = 0; r < RPW; ++r) if (act[r]) {                          \
      DOTS_DECL(r)                                                       \
      float mr = m[r];                                                   \
      float e0 = fexp2(t0-mr) + fexp2(t1-mr);                            \
      float e1 = fexp2(t2-mr) + fexp2(t3-mr);                            \
      float e2 = fexp2(t4-mr) + fexp2(t5-mr);                            \
      float e3 = fexp2(t6-mr) + fexp2(t7-mr);                            \
      S[r] += (e0+e1) + (e2+e3);                                         \
    }                                                                    \
  } while(0)

#define PHB(C) do {                                                      \
    int act[RPW]; int anyact = 0;                                        \
    _Pragma("unroll")                                                    \
    for (int r = 0; r < RPW; ++r) {                                      \
      act[r] = __any(cmax[C][r] > m[r] - THR);                           \
      anyact |= act[r];                                                  \
    }                                                                    \
    if (anyact) {                                                        \
      LOADB((C)*16);   PHB_HALF();                                       \
      LOADB((C)*16+8); PHB_HALF();                                       \
    }                                                                    \
  } while(0)

  PHB(0); PHB(1); PHB(2); PHB(3);

  // ---- merge + write ----
  #pragma unroll
  for (int r = 0; r < RPW; ++r) {
    float s = S[r];
    #pragma unroll
    for (int off = 32; off; off >>= 1) s += __shfl_xor(s, off, 64);
    float ch = 0.5f*(ptx[r]*ptx[r] + pty[r]*pty[r] + ptz[r]*ptz[r]) * INVK2;
    float res = fmaf(-EPSLN2, m[r] + flog2(s), ch + NEGEPSLOGW);
    if (lane == r) {
      if (mode) res = 0.5f*(hold[ridx0 + r] + res);
      outp[ridx0 + r] = res;
      ((float*)(pkout + (ridx0 + r)))[3] = (res - ch) * KSCALE;
    }
  }
#undef LOADB
#undef DOTS_DECL
#undef PHA_HALF
#undef PHB_HALF
#undef PHB
}

// Build the 6 packed column arrays once per launch. .w gets the h=0 initial Atilde.
__global__ void pack_init(const float* __restrict__ x, const float* __restrict__ y,
                          float4* pkfab, float4* pkgab,
                          float4* pkfaa0, float4* pkfaa1,
                          float4* pkgbb0, float4* pkgbb1)
{
  int i = blockIdx.x*256 + threadIdx.x;        // 0..16383 == b*4096+m
  const float* xp = x + (size_t)i*3;
  float xx = xp[0], xy = xp[1], xz = xp[2];
  float4 vx; vx.x=xx; vx.y=xy; vx.z=xz;
  vx.w = -0.5f*(xx*xx + xy*xy + xz*xz)*KSCALE;
  const float* yp = y + (size_t)i*4;
  float yx = yp[0], yy = yp[1], yz = yp[2];
  float4 vy; vy.x=yx; vy.y=yy; vy.z=yz;
  vy.w = -0.5f*(yx*yx + yy*yy + yz*yz)*KSCALE;
  pkgab[i]  = vx; pkfaa0[i] = vx; pkfaa1[i] = vx;
  pkfab[i]  = vy; pkgbb0[i] = vy; pkgbb1[i] = vy;
}

__global__ void reduce_kernel(const float* __restrict__ fab, const float* __restrict__ faa,
                              const float* __restrict__ gab, const float* __restrict__ gbb,
                              float* __restrict__ out)
{
  int b = blockIdx.x;
  int tid = threadIdx.x;
  float s = 0.f;
  for (int i = tid; i < NPTS; i += 256) {
    int idx = b*NPTS + i;
    s += (fab[idx] - faa[idx]) + (gab[idx] - gbb[idx]);
  }
  for (int off = 32; off > 0; off >>= 1) s += __shfl_down(s, off, 64);
  __shared__ float red[4];
  if ((tid & 63) == 0) red[tid >> 6] = s;
  __syncthreads();
  if (tid == 0) out[b] = (red[0]+red[1]+red[2]+red[3]) * (1.0f/NPTS);
}

extern "C" void kernel_launch(void* const* d_in, const int* in_sizes, int n_in,
                              void* d_out, int out_size, void* d_ws, size_t ws_size,
                              hipStream_t stream)
{
  const float* x = (const float*)d_in[0];   // (4,4096,3)
  const float* y = (const float*)d_in[1];   // (4,4096,4), first 3 comps used
  float* ws = (float*)d_ws;
  const size_t P = (size_t)NBATCH * NPTS;   // 16384

  float* f_ab    = ws + 0*P;
  float* g_ab    = ws + 1*P;
  float* faaR[2] = { ws + 2*P, ws + 4*P };
  float* gbbR[2] = { ws + 3*P, ws + 5*P };
  float4* pk4    = (float4*)(ws + 6*P);
  float4* PKfab    = pk4 + 0*P;             // cols = y, .w = Atilde(g_ab)
  float4* PKgab    = pk4 + 1*P;             // cols = x, .w = Atilde(f_ab)
  float4* PKfaa[2] = { pk4 + 2*P, pk4 + 3*P };
  float4* PKgbb[2] = { pk4 + 4*P, pk4 + 5*P };

  // zero h_old for the first averaged symmetric step (faaR[0], gbbR[0] contiguous)
  hipMemsetAsync(ws + 2*P, 0, 2*P*sizeof(float), stream);
  pack_init<<<dim3(P/256), dim3(256), 0, stream>>>(x, y, PKfab, PKgab,
                                                   PKfaa[0], PKfaa[1], PKgbb[0], PKgbb[1]);

  for (int i = 0; i < 21; ++i) {
    int cur = i & 1, nxt = cur ^ 1;
    int modeS = (i < 20) ? 1 : 0;    // averaged symmetric update except final softmin
    // phase 1: f_ab = softmin over y-cols (Atilde from g_ab)  ||  f_aa step
    softmin_kernel<<<1024, BLOCK, 0, stream>>>(
        x, 3, PKfab, PKgab, f_ab, f_ab, 0,
        x, 3, PKfaa[cur], PKfaa[nxt], faaR[cur], faaR[nxt], modeS);
    // phase 2: g_ab = softmin over x-cols (Atilde from f_ab)  ||  g_bb step
    softmin_kernel<<<1024, BLOCK, 0, stream>>>(
        y, 4, PKgab, PKfab, g_ab, g_ab, 0,
        y, 4, PKgbb[cur], PKgbb[nxt], gbbR[cur], gbbR[nxt], modeS);
  }
  // i=20 wrote faaR[1]/gbbR[1]
  reduce_kernel<<<dim3(4), dim3(256), 0, stream>>>(f_ab, faaR[1], g_ab, gbbR[1], (float*)d_out);
}

// Round 5
// 1683.010 us; speedup vs baseline: 1.0269x; 1.0269x over previous
//
#include <hip/hip_runtime.h>
#include <math.h>

#define NPTS 4096
#define NBATCH 4
#define BLOCK 256
#define RPW 8            // rows per wave (coords live in SGPRs)
#define NCHUNK 16        // 16 chunks x 4 float4/lane x 64 lanes = 4096 cols

static constexpr float KSCALE     = 1.4426950408889634f / 1e-4f;   // log2(e)/eps
static constexpr float INVK2      = 1.0f / (KSCALE * KSCALE);
static constexpr float EPSLN2     = 1e-4f * 0.6931471805599453f;   // eps*ln(2)
static constexpr float NEGEPSLOGW = 8.31776616671934e-4f;          // -eps * (-log(4096))
static constexpr float THR        = 26.0f;   // skip chunks with all t < M-26

__device__ __forceinline__ float fexp2(float x){
#if __has_builtin(__builtin_amdgcn_exp2f)
  return __builtin_amdgcn_exp2f(x);
#else
  return exp2f(x);
#endif
}
__device__ __forceinline__ float flog2(float x){
#if __has_builtin(__builtin_amdgcn_logf)
  return __builtin_amdgcn_logf(x);
#else
  return log2f(x);
#endif
}
__device__ __forceinline__ float frl(float x){
  return __int_as_float(__builtin_amdgcn_readfirstlane(__float_as_int(x)));
}

// One launch = two independent softmin problems (512 blocks each).
// Block = 256 thr = 4 independent waves (no LDS, no barriers).
// Wave owns 8 rows; row coords are wave-uniform -> forced into SGPRs via
// readfirstlane (v_fma takes 1 SGPR source). Columns lane-distinct
// (lane l owns cols l+64j), 4 coalesced float4 loads per chunk, reused
// across 8 rows. Per-(lane,row) online LSE; wave-vote skip of the
// exp2 block when a chunk provably can't contribute (>2^-26 rel).
// Final: 6-step shfl max + single rescale + 6-step shfl sum per row.
__global__ __launch_bounds__(BLOCK, 4) void softmin_kernel(
    const float* __restrict__ rowA, int rsA, const float4* __restrict__ pkInA,
    float4* __restrict__ pkOutA, const float* __restrict__ hOldA,
    float* __restrict__ outA, int modeA,
    const float* __restrict__ rowB, int rsB, const float4* __restrict__ pkInB,
    float4* __restrict__ pkOutB, const float* __restrict__ hOldB,
    float* __restrict__ outB, int modeB)
{
  int bid = blockIdx.x;
  const float* rowp; const float4* pkin; float4* pkout; const float* hold;
  float* outp; int rs, mode;
  if (bid < 512) { rowp=rowA; pkin=pkInA; pkout=pkOutA; hold=hOldA; outp=outA; rs=rsA; mode=modeA; }
  else           { rowp=rowB; pkin=pkInB; pkout=pkOutB; hold=hOldB; outp=outB; rs=rsB; mode=modeB; }
  int lb = bid & 511;
  int b  = lb >> 7;          // batch
  int rb = lb & 127;         // row-block (32 rows per block)

  int tid = threadIdx.x;
  int lane = tid & 63;
  int wu = __builtin_amdgcn_readfirstlane(tid >> 6);
  int r0 = rb*32 + wu*RPW;
  int ridx0 = b*NPTS + r0;

  // wave-uniform row coords -> SGPRs
  float sx[RPW], sy[RPW], sz[RPW];
  #pragma unroll
  for (int i = 0; i < RPW; ++i) {
    const float* p = rowp + (size_t)(ridx0 + i) * rs;
    sx[i] = frl(p[0]*KSCALE); sy[i] = frl(p[1]*KSCALE); sz[i] = frl(p[2]*KSCALE);
  }

  float M[RPW], S[RPW];
  #pragma unroll
  for (int i = 0; i < RPW; ++i) { M[i] = -INFINITY; S[i] = 0.f; }

  const float4* pk = pkin + b*NPTS + lane;

  for (int c = 0; c < NCHUNK; ++c) {
    float4 q0 = pk[0], q1 = pk[64], q2 = pk[128], q3 = pk[192];
    pk += 256;
    #pragma unroll
    for (int r = 0; r < RPW; ++r) {
      float t0 = fmaf(sx[r],q0.x,fmaf(sy[r],q0.y,fmaf(sz[r],q0.z,q0.w)));
      float t1 = fmaf(sx[r],q1.x,fmaf(sy[r],q1.y,fmaf(sz[r],q1.z,q1.w)));
      float t2 = fmaf(sx[r],q2.x,fmaf(sy[r],q2.y,fmaf(sz[r],q2.z,q2.w)));
      float t3 = fmaf(sx[r],q3.x,fmaf(sy[r],q3.y,fmaf(sz[r],q3.z,q3.w)));
      float cmax = fmaxf(fmaxf(t0,t1), fmaxf(t2,t3));
      if (__any(cmax > M[r] - THR)) {
        float Mn = fmaxf(M[r], cmax);
        float sc = fexp2(M[r]-Mn);
        float e  = (fexp2(t0-Mn) + fexp2(t1-Mn)) + (fexp2(t2-Mn) + fexp2(t3-Mn));
        S[r] = fmaf(S[r], sc, e);
        M[r] = Mn;
      }
    }
  }

  // cross-lane merge per row: global max -> single rescale -> sum
  #pragma unroll
  for (int r = 0; r < RPW; ++r) {
    float m = M[r];
    #pragma unroll
    for (int off = 32; off; off >>= 1) m = fmaxf(m, __shfl_xor(m, off, 64));
    float s = S[r] * fexp2(M[r] - m);
    #pragma unroll
    for (int off = 32; off; off >>= 1) s += __shfl_xor(s, off, 64);
    float ch = 0.5f*(sx[r]*sx[r] + sy[r]*sy[r] + sz[r]*sz[r]) * INVK2;
    float res = fmaf(-EPSLN2, m + flog2(s), ch + NEGEPSLOGW);
    if (lane == r) {
      if (mode) res = 0.5f*(hold[ridx0 + r] + res);
      outp[ridx0 + r] = res;
      ((float*)(pkout + (ridx0 + r)))[3] = (res - ch) * KSCALE;
    }
  }
}

// Build the 6 packed column arrays once per launch. .w gets the h=0 initial Atilde.
__global__ void pack_init(const float* __restrict__ x, const float* __restrict__ y,
                          float4* pkfab, float4* pkgab,
                          float4* pkfaa0, float4* pkfaa1,
                          float4* pkgbb0, float4* pkgbb1)
{
  int i = blockIdx.x*256 + threadIdx.x;        // 0..16383 == b*4096+m
  const float* xp = x + (size_t)i*3;
  float xx = xp[0], xy = xp[1], xz = xp[2];
  float4 vx; vx.x=xx; vx.y=xy; vx.z=xz;
  vx.w = -0.5f*(xx*xx + xy*xy + xz*xz)*KSCALE;
  const float* yp = y + (size_t)i*4;
  float yx = yp[0], yy = yp[1], yz = yp[2];
  float4 vy; vy.x=yx; vy.y=yy; vy.z=yz;
  vy.w = -0.5f*(yx*yx + yy*yy + yz*yz)*KSCALE;
  pkgab[i]  = vx; pkfaa0[i] = vx; pkfaa1[i] = vx;
  pkfab[i]  = vy; pkgbb0[i] = vy; pkgbb1[i] = vy;
}

__global__ void reduce_kernel(const float* __restrict__ fab, const float* __restrict__ faa,
                              const float* __restrict__ gab, const float* __restrict__ gbb,
                              float* __restrict__ out)
{
  int b = blockIdx.x;
  int tid = threadIdx.x;
  float s = 0.f;
  for (int i = tid; i < NPTS; i += 256) {
    int idx = b*NPTS + i;
    s += (fab[idx] - faa[idx]) + (gab[idx] - gbb[idx]);
  }
  for (int off = 32; off > 0; off >>= 1) s += __shfl_down(s, off, 64);
  __shared__ float red[4];
  if ((tid & 63) == 0) red[tid >> 6] = s;
  __syncthreads();
  if (tid == 0) out[b] = (red[0]+red[1]+red[2]+red[3]) * (1.0f/NPTS);
}

extern "C" void kernel_launch(void* const* d_in, const int* in_sizes, int n_in,
                              void* d_out, int out_size, void* d_ws, size_t ws_size,
                              hipStream_t stream)
{
  const float* x = (const float*)d_in[0];   // (4,4096,3)
  const float* y = (const float*)d_in[1];   // (4,4096,4), first 3 comps used
  float* ws = (float*)d_ws;
  const size_t P = (size_t)NBATCH * NPTS;   // 16384

  float* f_ab    = ws + 0*P;
  float* g_ab    = ws + 1*P;
  float* faaR[2] = { ws + 2*P, ws + 4*P };
  float* gbbR[2] = { ws + 3*P, ws + 5*P };
  float4* pk4    = (float4*)(ws + 6*P);
  float4* PKfab    = pk4 + 0*P;             // cols = y, .w = Atilde(g_ab)
  float4* PKgab    = pk4 + 1*P;             // cols = x, .w = Atilde(f_ab)
  float4* PKfaa[2] = { pk4 + 2*P, pk4 + 3*P };
  float4* PKgbb[2] = { pk4 + 4*P, pk4 + 5*P };

  // zero h_old for the first averaged symmetric step (faaR[0], gbbR[0] contiguous)
  hipMemsetAsync(ws + 2*P, 0, 2*P*sizeof(float), stream);
  pack_init<<<dim3(P/256), dim3(256), 0, stream>>>(x, y, PKfab, PKgab,
                                                   PKfaa[0], PKfaa[1], PKgbb[0], PKgbb[1]);

  for (int i = 0; i < 21; ++i) {
    int cur = i & 1, nxt = cur ^ 1;
    int modeS = (i < 20) ? 1 : 0;    // averaged symmetric update except final softmin
    // phase 1: f_ab = softmin over y-cols (Atilde from g_ab)  ||  f_aa step
    softmin_kernel<<<1024, BLOCK, 0, stream>>>(
        x, 3, PKfab, PKgab, f_ab, f_ab, 0,
        x, 3, PKfaa[cur], PKfaa[nxt], faaR[cur], faaR[nxt], modeS);
    // phase 2: g_ab = softmin over x-cols (Atilde from f_ab)  ||  g_bb step
    softmin_kernel<<<1024, BLOCK, 0, stream>>>(
        y, 4, PKgab, PKfab, g_ab, g_ab, 0,
        y, 4, PKgbb[cur], PKgbb[nxt], gbbR[cur], gbbR[nxt], modeS);
  }
  // i=20 wrote faaR[1]/gbbR[1]
  reduce_kernel<<<dim3(4), dim3(256), 0, stream>>>(f_ab, faaR[1], g_ab, gbbR[1], (float*)d_out);
}